// Round 1
// 392.297 us; speedup vs baseline: 1.0431x; 1.0431x over previous
//
#include <hip/hip_runtime.h>

// Problem constants (from reference setup_inputs)
constexpr int B  = 16;
constexpr int C  = 3;
constexpr int H  = 768;
constexpr int W  = 1024;
constexpr int HW = H * W;

// Tiling: each block computes a TX x TY pixel tile; second is staged in LDS
// with an R-pixel halo (clamped at image borders). Gathers whose corners fall
// outside the halo (P ~ 6e-7 per pixel for N(0,1) flow) take a global fallback.
constexpr int TX = 64;                 // tile width (pixels)
constexpr int TY = 16;                 // tile height (pixels)
constexpr int R  = 5;                  // halo radius
constexpr int TCOLS = TX + 2 * R + 1;  // 75 staged columns (x0..x0+1 coverage)
constexpr int TROWS = TY + 2 * R + 1;  // 27 staged rows
constexpr int TSTR  = TCOLS + 1;       // 76 padded LDS row stride (floats)
constexpr int NXT = W / TX;            // 16 tiles in x
constexpr int NYT = H / TY;            // 48 tiles in y
constexpr int NWG = B * NXT * NYT;     // 12288 workgroups
constexpr int NXCD = 8;
constexpr int PERX = NWG / NXCD;       // 1536 (NWG % 8 == 0 -> bijective swizzle)

__global__ __launch_bounds__(256) void warp_l1_mean_tiled(
    const float* __restrict__ first,
    const float* __restrict__ second,
    const float* __restrict__ flow,
    const float* __restrict__ alpha,
    float* __restrict__ out)
{
    __shared__ float tile[C][TROWS][TSTR];  // 3*27*76*4 = 24,624 B -> 6 blocks/CU

    // XCD-aware bijective swizzle: consecutive HW block ids round-robin XCDs,
    // so remap such that each XCD owns a contiguous work range (= 2 batches);
    // neighboring tiles' halo re-reads then hit the same XCD's L2.
    const int hw  = blockIdx.x;
    const int wid = (hw & (NXCD - 1)) * PERX + (hw >> 3);

    const int b   = wid / (NXT * NYT);
    const int r0  = wid - b * (NXT * NYT);
    const int tyi = r0 / NXT;
    const int txi = r0 - tyi * NXT;

    const int x_base = txi * TX;
    const int y_base = tyi * TY;
    const int x_lo   = x_base - R;
    const int y_lo   = y_base - R;

    const float* __restrict__ sec = second + (size_t)b * C * HW;
    const float* __restrict__ fst = first  + (size_t)b * C * HW;
    const float* __restrict__ fl  = flow   + (size_t)b * 2 * HW;
    float*       __restrict__ op  = out    + (size_t)b * HW;

    // ---- Stage clamped second-tile into LDS (coalesced; 3 channels/pixel) ----
    for (int j = threadIdx.x; j < TROWS * TCOLS; j += 256) {
        const int r  = j / TCOLS;
        const int cc = j - r * TCOLS;
        const int gx = min(max(x_lo + cc, 0), W - 1);
        const int gy = min(max(y_lo + r,  0), H - 1);
        const int idx = gy * W + gx;
        tile[0][r][cc] = sec[idx];
        tile[1][r][cc] = sec[HW + idx];
        tile[2][r][cc] = sec[2 * HW + idx];
    }
    __syncthreads();

    // wave n handles rows (n, n+4, n+8, n+12) of the tile; lanes = consecutive x
    const int px  = threadIdx.x & 63;
    const int py0 = threadIdx.x >> 6;
    const int x   = x_base + px;
    const float a = alpha[0];

#pragma unroll
    for (int k = 0; k < 4; ++k) {
        const int y = y_base + py0 + 4 * k;
        const int p = y * W + x;

        const float fx = fl[p];
        const float fy = fl[HW + p];

        const float ix = (float)x + fx * ((float)W / (float)(W - 1));
        const float iy = (float)y + fy * ((float)H / (float)(H - 1));

        const float x0f = floorf(ix);
        const float y0f = floorf(iy);
        const float wx1 = ix - x0f;
        const float wy1 = iy - y0f;
        const float wx0 = 1.0f - wx1;
        const float wy0 = 1.0f - wy1;

        const int x0 = (int)x0f;
        const int y0 = (int)y0f;
        const int x1 = x0 + 1;
        const int y1 = y0 + 1;

        // validity from UNclipped coords; invalid corners contribute exactly 0
        const bool vx0 = (x0 >= 0) && (x0 < W);
        const bool vx1 = (x1 >= 0) && (x1 < W);
        const bool vy0 = (y0 >= 0) && (y0 < H);
        const bool vy1 = (y1 >= 0) && (y1 < H);

        const float w00 = wy0 * wx0 * ((vx0 && vy0) ? 1.0f : 0.0f);
        const float w01 = wy0 * wx1 * ((vx1 && vy0) ? 1.0f : 0.0f);
        const float w10 = wy1 * wx0 * ((vx0 && vy1) ? 1.0f : 0.0f);
        const float w11 = wy1 * wx1 * ((vx1 && vy1) ? 1.0f : 0.0f);

        const int lx = x0 - x_lo;
        const int ly = y0 - y_lo;

        float acc = 0.0f;
        if ((unsigned)lx < (unsigned)(TCOLS - 1) &&
            (unsigned)ly < (unsigned)(TROWS - 1)) {
            // fast path: all 4 corners inside the staged tile (halo values are
            // clamped copies, but any out-of-image corner has weight == 0)
#pragma unroll
            for (int c = 0; c < C; ++c) {
                const float* tp = &tile[c][ly][lx];
                const float v00 = tp[0];
                const float v01 = tp[1];
                const float v10 = tp[TSTR];
                const float v11 = tp[TSTR + 1];
                const float warped = w00 * v00 + w01 * v01 + w10 * v10 + w11 * v11;
                acc += fabsf(fst[c * HW + p] - warped);
            }
        } else {
            // rare fallback (|flow| > halo): identical math via global gather
            const int cx0 = min(max(x0, 0), W - 1);
            const int cx1 = min(max(x1, 0), W - 1);
            const int cy0 = min(max(y0, 0), H - 1);
            const int cy1 = min(max(y1, 0), H - 1);
            const int i00 = cy0 * W + cx0;
            const int i01 = cy0 * W + cx1;
            const int i10 = cy1 * W + cx0;
            const int i11 = cy1 * W + cx1;
#pragma unroll
            for (int c = 0; c < C; ++c) {
                const float* s = sec + c * HW;
                const float warped = w00 * s[i00] + w01 * s[i01]
                                   + w10 * s[i10] + w11 * s[i11];
                acc += fabsf(fst[c * HW + p] - warped);
            }
        }

        op[p] = a * (acc * (1.0f / 3.0f));
    }
}

extern "C" void kernel_launch(void* const* d_in, const int* in_sizes, int n_in,
                              void* d_out, int out_size, void* d_ws, size_t ws_size,
                              hipStream_t stream) {
    const float* first  = (const float*)d_in[0];
    const float* second = (const float*)d_in[1];
    const float* flow   = (const float*)d_in[2];
    const float* alpha  = (const float*)d_in[3];
    float* out = (float*)d_out;

    warp_l1_mean_tiled<<<NWG, 256, 0, stream>>>(first, second, flow, alpha, out);
}

// Round 2
// 380.696 us; speedup vs baseline: 1.0749x; 1.0305x over previous
//
#include <hip/hip_runtime.h>

// Problem constants (from reference setup_inputs)
constexpr int B  = 16;
constexpr int C  = 3;
constexpr int H  = 768;
constexpr int W  = 1024;
constexpr int HW = H * W;

// Tiling: each block computes a TX x TY pixel tile; second is staged in LDS
// with an R-pixel halo (clamped at image borders). Gathers whose corners fall
// outside the halo (P(|N(0,1)|>4) ~ 3e-5 per corner) take a global fallback.
constexpr int TX = 64;                 // tile width (pixels)
constexpr int TY = 16;                 // tile height (pixels)
constexpr int R  = 4;                  // halo radius
constexpr int TCOLS = TX + 2 * R + 1;  // 73 staged columns (x0..x0+1 coverage)
constexpr int TROWS = TY + 2 * R + 1;  // 25 staged rows
constexpr int CPR   = 19;              // float4 chunks per row (19*4=76 >= 73)
constexpr int TSTR  = 77;              // LDS row stride; 77 % 32 = 13 (odd) -> bank dispersal
constexpr int NXT = W / TX;            // 16 tiles in x
constexpr int NYT = H / TY;            // 48 tiles in y
constexpr int NWG = B * NXT * NYT;     // 12288 workgroups
constexpr int NXCD = 8;
constexpr int PERX = NWG / NXCD;       // 1536 (NWG % 8 == 0 -> bijective swizzle)

__global__ __launch_bounds__(256) void warp_l1_mean_tiled(
    const float* __restrict__ first,
    const float* __restrict__ second,
    const float* __restrict__ flow,
    const float* __restrict__ alpha,
    float* __restrict__ out)
{
    __shared__ float tile[C * TROWS * TSTR];  // 3*25*77*4 = 23,100 B -> 7 blocks/CU

    // XCD-aware bijective swizzle (NWG % 8 == 0): each XCD owns a contiguous
    // range (= 2 batches) so neighboring tiles' halo re-reads hit its L2.
    const int hw  = blockIdx.x;
    const int wid = (hw & (NXCD - 1)) * PERX + (hw >> 3);

    const int b   = wid / (NXT * NYT);
    const int r0  = wid - b * (NXT * NYT);
    const int tyi = r0 / NXT;
    const int txi = r0 - tyi * NXT;

    const int x_base = txi * TX;
    const int y_base = tyi * TY;
    const int x_lo   = x_base - R;     // = 64*txi - 4: 16B-aligned float4 base
    const int y_lo   = y_base - R;

    const float* __restrict__ sec = second + (size_t)b * C * HW;
    const float* __restrict__ fst = first  + (size_t)b * C * HW;
    const float* __restrict__ fl  = flow   + (size_t)b * 2 * HW;
    float*       __restrict__ op  = out    + (size_t)b * HW;

    // wave n handles rows (n, n+4, n+8, n+12); lanes = consecutive x
    const int px  = threadIdx.x & 63;
    const int py0 = threadIdx.x >> 6;
    const int x   = x_base + px;

    // ---- Prefetch flow + first into registers BEFORE staging/barrier so the
    //      post-barrier compute doesn't stall on their global latency. ----
    float pfx[4], pfy[4], pf0[4], pf1[4], pf2[4];
#pragma unroll
    for (int k = 0; k < 4; ++k) {
        const int p = (y_base + py0 + 4 * k) * W + x;
        pfx[k] = fl[p];
        pfy[k] = fl[HW + p];
        pf0[k] = fst[p];
        pf1[k] = fst[HW + p];
        pf2[k] = fst[2 * HW + p];
    }

    // ---- Stage clamped second-tile into LDS, float4 per chunk where the
    //      whole chunk is in-bounds (all chunks of interior tiles), scalar
    //      clamped gathers otherwise (image-border tiles only). ----
    for (int j = threadIdx.x; j < C * TROWS * CPR; j += 256) {
        const int ch  = j / (TROWS * CPR);
        const int rem = j - ch * (TROWS * CPR);
        const int r   = rem / CPR;
        const int q   = rem - r * CPR;
        const int gy  = y_lo + r;
        const int gx0 = x_lo + 4 * q;
        const float* __restrict__ src = sec + (size_t)ch * HW;
        float4 v;
        if ((unsigned)gy < (unsigned)H && gx0 >= 0 && gx0 + 3 < W) {
            v = *reinterpret_cast<const float4*>(src + gy * W + gx0);
        } else {
            const int cyW = min(max(gy, 0), H - 1) * W;
            v.x = src[cyW + min(max(gx0,     0), W - 1)];
            v.y = src[cyW + min(max(gx0 + 1, 0), W - 1)];
            v.z = src[cyW + min(max(gx0 + 2, 0), W - 1)];
            v.w = src[cyW + min(max(gx0 + 3, 0), W - 1)];
        }
        float* dst = &tile[(ch * TROWS + r) * TSTR + 4 * q];
        dst[0] = v.x; dst[1] = v.y; dst[2] = v.z; dst[3] = v.w;
    }
    __syncthreads();

    const float a3 = alpha[0] * (1.0f / 3.0f);

#pragma unroll
    for (int k = 0; k < 4; ++k) {
        const int y = y_base + py0 + 4 * k;
        const int p = y * W + x;

        const float ix = (float)x + pfx[k] * ((float)W / (float)(W - 1));
        const float iy = (float)y + pfy[k] * ((float)H / (float)(H - 1));

        const float x0f = floorf(ix);
        const float y0f = floorf(iy);
        const float wx1 = ix - x0f;
        const float wy1 = iy - y0f;
        const float wx0 = 1.0f - wx1;
        const float wy0 = 1.0f - wy1;

        const int x0 = (int)x0f;
        const int y0 = (int)y0f;
        const int x1 = x0 + 1;
        const int y1 = y0 + 1;

        // validity from UNclipped coords; invalid corners contribute exactly 0
        const bool vx0 = (x0 >= 0) && (x0 < W);
        const bool vx1 = (x1 >= 0) && (x1 < W);
        const bool vy0 = (y0 >= 0) && (y0 < H);
        const bool vy1 = (y1 >= 0) && (y1 < H);

        const float w00 = wy0 * wx0 * ((vx0 && vy0) ? 1.0f : 0.0f);
        const float w01 = wy0 * wx1 * ((vx1 && vy0) ? 1.0f : 0.0f);
        const float w10 = wy1 * wx0 * ((vx0 && vy1) ? 1.0f : 0.0f);
        const float w11 = wy1 * wx1 * ((vx1 && vy1) ? 1.0f : 0.0f);

        const int lx = x0 - x_lo;
        const int ly = y0 - y_lo;

        float acc;
        if ((unsigned)lx < (unsigned)(TCOLS - 1) &&
            (unsigned)ly < (unsigned)(TROWS - 1)) {
            // fast path: all 4 corners inside the staged tile (halo values are
            // clamped copies, but any out-of-image corner has weight == 0)
            const float* tp0 = &tile[(0 * TROWS + ly) * TSTR + lx];
            const float* tp1 = &tile[(1 * TROWS + ly) * TSTR + lx];
            const float* tp2 = &tile[(2 * TROWS + ly) * TSTR + lx];
            const float wa = w00 * tp0[0] + w01 * tp0[1] + w10 * tp0[TSTR] + w11 * tp0[TSTR + 1];
            const float wb = w00 * tp1[0] + w01 * tp1[1] + w10 * tp1[TSTR] + w11 * tp1[TSTR + 1];
            const float wc = w00 * tp2[0] + w01 * tp2[1] + w10 * tp2[TSTR] + w11 * tp2[TSTR + 1];
            acc = fabsf(pf0[k] - wa) + fabsf(pf1[k] - wb) + fabsf(pf2[k] - wc);
        } else {
            // rare fallback (|flow| > halo): identical math via global gather
            const int cx0 = min(max(x0, 0), W - 1);
            const int cx1 = min(max(x1, 0), W - 1);
            const int cy0 = min(max(y0, 0), H - 1);
            const int cy1 = min(max(y1, 0), H - 1);
            const int i00 = cy0 * W + cx0;
            const int i01 = cy0 * W + cx1;
            const int i10 = cy1 * W + cx0;
            const int i11 = cy1 * W + cx1;
            const float wa = w00 * sec[i00] + w01 * sec[i01] + w10 * sec[i10] + w11 * sec[i11];
            const float wb = w00 * sec[HW + i00] + w01 * sec[HW + i01] + w10 * sec[HW + i10] + w11 * sec[HW + i11];
            const float wc = w00 * sec[2*HW + i00] + w01 * sec[2*HW + i01] + w10 * sec[2*HW + i10] + w11 * sec[2*HW + i11];
            acc = fabsf(pf0[k] - wa) + fabsf(pf1[k] - wb) + fabsf(pf2[k] - wc);
        }

        op[p] = a3 * acc;
    }
}

extern "C" void kernel_launch(void* const* d_in, const int* in_sizes, int n_in,
                              void* d_out, int out_size, void* d_ws, size_t ws_size,
                              hipStream_t stream) {
    const float* first  = (const float*)d_in[0];
    const float* second = (const float*)d_in[1];
    const float* flow   = (const float*)d_in[2];
    const float* alpha  = (const float*)d_in[3];
    float* out = (float*)d_out;

    warp_l1_mean_tiled<<<NWG, 256, 0, stream>>>(first, second, flow, alpha, out);
}

// Round 3
// 368.460 us; speedup vs baseline: 1.1106x; 1.0332x over previous
//
#include <hip/hip_runtime.h>

// Problem constants (from reference setup_inputs)
constexpr int B  = 16;
constexpr int C  = 3;
constexpr int H  = 768;
constexpr int W  = 1024;
constexpr int HW = H * W;

// Tiling: each block computes a TX x TY pixel tile; second is staged in LDS
// with an R-pixel halo (clamped at image borders). Gathers whose corners fall
// outside the halo (P(|N(0,1)|>4) ~ 3e-5 per corner) take a global fallback.
// TY=32 @ 512 threads: LDS = 3*41*76*4 = 37,392 B -> 4 blocks/CU * 8 waves
// = 32 waves/CU (100% occupancy), vs 6 blocks * 4 waves = 24 at TY=16.
constexpr int TX = 64;                 // tile width (pixels)
constexpr int TY = 32;                 // tile height (pixels)
constexpr int NT = 512;                // threads per block
constexpr int R  = 4;                  // halo radius
constexpr int TCOLS = TX + 2 * R + 1;  // 73 staged columns (x0..x0+1 coverage)
constexpr int TROWS = TY + 2 * R + 1;  // 41 staged rows
constexpr int CPR   = 19;              // float4 chunks per row (19*4=76 >= 73)
constexpr int TSTR  = 76;              // LDS row stride (floats); rows 16B-aligned
constexpr int NXT = W / TX;            // 16 tiles in x
constexpr int NYT = H / TY;            // 24 tiles in y
constexpr int NWG = B * NXT * NYT;     // 6144 workgroups
constexpr int NXCD = 8;
constexpr int PERX = NWG / NXCD;       // 768 (NWG % 8 == 0 -> bijective swizzle)

__global__ __launch_bounds__(NT, 8) void warp_l1_mean_tiled(
    const float* __restrict__ first,
    const float* __restrict__ second,
    const float* __restrict__ flow,
    const float* __restrict__ alpha,
    float* __restrict__ out)
{
    __shared__ float tile[C * TROWS * TSTR];  // 37,392 B

    // XCD-aware bijective swizzle (NWG % 8 == 0): each XCD owns a contiguous
    // range so neighboring tiles' halo re-reads hit its private L2.
    const int hw  = blockIdx.x;
    const int wid = (hw & (NXCD - 1)) * PERX + (hw >> 3);

    const int b   = wid / (NXT * NYT);
    const int r0  = wid - b * (NXT * NYT);
    const int tyi = r0 / NXT;
    const int txi = r0 - tyi * NXT;

    const int x_base = txi * TX;
    const int y_base = tyi * TY;
    const int x_lo   = x_base - R;     // multiple of 4 -> 16B-aligned float4 base
    const int y_lo   = y_base - R;

    const float* __restrict__ sec = second + (size_t)b * C * HW;
    const float* __restrict__ fst = first  + (size_t)b * C * HW;
    const float* __restrict__ fl  = flow   + (size_t)b * 2 * HW;
    float*       __restrict__ op  = out    + (size_t)b * HW;

    // wave n handles rows (n, n+8, n+16, n+24); lanes = consecutive x
    const int px  = threadIdx.x & 63;
    const int py0 = threadIdx.x >> 6;  // 0..7
    const int x   = x_base + px;

    // ---- Prefetch flow + first into registers BEFORE staging/barrier.
    //      Non-temporal: zero-reuse streams must not evict second's halo
    //      lines from L2. ----
    float pfx[4], pfy[4], pf0[4], pf1[4], pf2[4];
#pragma unroll
    for (int k = 0; k < 4; ++k) {
        const int p = (y_base + py0 + 8 * k) * W + x;
        pfx[k] = __builtin_nontemporal_load(fl + p);
        pfy[k] = __builtin_nontemporal_load(fl + HW + p);
        pf0[k] = __builtin_nontemporal_load(fst + p);
        pf1[k] = __builtin_nontemporal_load(fst + HW + p);
        pf2[k] = __builtin_nontemporal_load(fst + 2 * HW + p);
    }

    // ---- Stage clamped second-tile into LDS, float4 per chunk where the
    //      whole chunk is in-bounds (all chunks of interior tiles), scalar
    //      clamped gathers otherwise (image-border tiles only). ----
    for (int j = threadIdx.x; j < C * TROWS * CPR; j += NT) {
        const int ch  = j / (TROWS * CPR);
        const int rem = j - ch * (TROWS * CPR);
        const int r   = rem / CPR;
        const int q   = rem - r * CPR;
        const int gy  = y_lo + r;
        const int gx0 = x_lo + 4 * q;
        const float* __restrict__ src = sec + (size_t)ch * HW;
        float4 v;
        if ((unsigned)gy < (unsigned)H && gx0 >= 0 && gx0 + 3 < W) {
            v = *reinterpret_cast<const float4*>(src + gy * W + gx0);
        } else {
            const int cyW = min(max(gy, 0), H - 1) * W;
            v.x = src[cyW + min(max(gx0,     0), W - 1)];
            v.y = src[cyW + min(max(gx0 + 1, 0), W - 1)];
            v.z = src[cyW + min(max(gx0 + 2, 0), W - 1)];
            v.w = src[cyW + min(max(gx0 + 3, 0), W - 1)];
        }
        float* dst = &tile[(ch * TROWS + r) * TSTR + 4 * q];
        dst[0] = v.x; dst[1] = v.y; dst[2] = v.z; dst[3] = v.w;
    }
    __syncthreads();

    const float a3 = alpha[0] * (1.0f / 3.0f);

#pragma unroll
    for (int k = 0; k < 4; ++k) {
        const int y = y_base + py0 + 8 * k;
        const int p = y * W + x;

        const float ix = (float)x + pfx[k] * ((float)W / (float)(W - 1));
        const float iy = (float)y + pfy[k] * ((float)H / (float)(H - 1));

        const float x0f = floorf(ix);
        const float y0f = floorf(iy);
        const float wx1 = ix - x0f;
        const float wy1 = iy - y0f;
        const float wx0 = 1.0f - wx1;
        const float wy0 = 1.0f - wy1;

        const int x0 = (int)x0f;
        const int y0 = (int)y0f;
        const int x1 = x0 + 1;
        const int y1 = y0 + 1;

        // validity from UNclipped coords; invalid corners contribute exactly 0
        const bool vx0 = (x0 >= 0) && (x0 < W);
        const bool vx1 = (x1 >= 0) && (x1 < W);
        const bool vy0 = (y0 >= 0) && (y0 < H);
        const bool vy1 = (y1 >= 0) && (y1 < H);

        const float w00 = wy0 * wx0 * ((vx0 && vy0) ? 1.0f : 0.0f);
        const float w01 = wy0 * wx1 * ((vx1 && vy0) ? 1.0f : 0.0f);
        const float w10 = wy1 * wx0 * ((vx0 && vy1) ? 1.0f : 0.0f);
        const float w11 = wy1 * wx1 * ((vx1 && vy1) ? 1.0f : 0.0f);

        const int lx = x0 - x_lo;
        const int ly = y0 - y_lo;

        float acc;
        if ((unsigned)lx < (unsigned)(TCOLS - 1) &&
            (unsigned)ly < (unsigned)(TROWS - 1)) {
            // fast path: all 4 corners inside the staged tile (halo values are
            // clamped copies, but any out-of-image corner has weight == 0)
            const float* tp0 = &tile[(0 * TROWS + ly) * TSTR + lx];
            const float* tp1 = &tile[(1 * TROWS + ly) * TSTR + lx];
            const float* tp2 = &tile[(2 * TROWS + ly) * TSTR + lx];
            const float wa = w00 * tp0[0] + w01 * tp0[1] + w10 * tp0[TSTR] + w11 * tp0[TSTR + 1];
            const float wb = w00 * tp1[0] + w01 * tp1[1] + w10 * tp1[TSTR] + w11 * tp1[TSTR + 1];
            const float wc = w00 * tp2[0] + w01 * tp2[1] + w10 * tp2[TSTR] + w11 * tp2[TSTR + 1];
            acc = fabsf(pf0[k] - wa) + fabsf(pf1[k] - wb) + fabsf(pf2[k] - wc);
        } else {
            // rare fallback (|flow| > halo): identical math via global gather
            const int cx0 = min(max(x0, 0), W - 1);
            const int cx1 = min(max(x1, 0), W - 1);
            const int cy0 = min(max(y0, 0), H - 1);
            const int cy1 = min(max(y1, 0), H - 1);
            const int i00 = cy0 * W + cx0;
            const int i01 = cy0 * W + cx1;
            const int i10 = cy1 * W + cx0;
            const int i11 = cy1 * W + cx1;
            const float wa = w00 * sec[i00] + w01 * sec[i01] + w10 * sec[i10] + w11 * sec[i11];
            const float wb = w00 * sec[HW + i00] + w01 * sec[HW + i01] + w10 * sec[HW + i10] + w11 * sec[HW + i11];
            const float wc = w00 * sec[2*HW + i00] + w01 * sec[2*HW + i01] + w10 * sec[2*HW + i10] + w11 * sec[2*HW + i11];
            acc = fabsf(pf0[k] - wa) + fabsf(pf1[k] - wb) + fabsf(pf2[k] - wc);
        }

        __builtin_nontemporal_store(a3 * acc, op + p);
    }
}

extern "C" void kernel_launch(void* const* d_in, const int* in_sizes, int n_in,
                              void* d_out, int out_size, void* d_ws, size_t ws_size,
                              hipStream_t stream) {
    const float* first  = (const float*)d_in[0];
    const float* second = (const float*)d_in[1];
    const float* flow   = (const float*)d_in[2];
    const float* alpha  = (const float*)d_in[3];
    float* out = (float*)d_out;

    warp_l1_mean_tiled<<<NWG, NT, 0, stream>>>(first, second, flow, alpha, out);
}

// Round 4
// 367.496 us; speedup vs baseline: 1.1135x; 1.0026x over previous
//
#include <hip/hip_runtime.h>

// Problem constants (from reference setup_inputs)
constexpr int B  = 16;
constexpr int C  = 3;
constexpr int H  = 768;
constexpr int W  = 1024;
constexpr int HW = H * W;

// Tiling: each block computes a TX x TY pixel tile; second is staged in LDS
// with an R-pixel halo (clamped at image borders). Gathers whose corners fall
// outside the halo (P(|N(0,1)|>4) ~ 3e-5 per corner) take a global fallback.
// TY=32 @ 512 threads: LDS = 3*41*80*4 = 39,360 B -> 4 blocks/CU * 8 waves
// = 32 waves/CU.
// Row stride 80: s = 80 mod 32 = 16 -> ds_read bank shift from Drow=+-1 is
// +-16 (one collision window), Drow=+-2 is 0 (merges into the free half-wave
// 2-way). Stride 76 (s=12) measured 8.8M conflict cycles; 77 (s=13) 13.15M.
constexpr int TX = 64;                 // tile width (pixels)
constexpr int TY = 32;                 // tile height (pixels)
constexpr int NT = 512;                // threads per block
constexpr int R  = 4;                  // halo radius
constexpr int TCOLS = TX + 2 * R + 1;  // 73 staged columns (x0..x0+1 coverage)
constexpr int TROWS = TY + 2 * R + 1;  // 41 staged rows
constexpr int CPR   = 19;              // float4 chunks per row (19*4=76 >= 73)
constexpr int TSTR  = 80;              // LDS row stride (floats), 16B-aligned rows
constexpr int NXT = W / TX;            // 16 tiles in x
constexpr int NYT = H / TY;            // 24 tiles in y
constexpr int NWG = B * NXT * NYT;     // 6144 workgroups
constexpr int NXCD = 8;
constexpr int PERX = NWG / NXCD;       // 768 (NWG % 8 == 0 -> bijective swizzle)

__global__ __launch_bounds__(NT, 8) void warp_l1_mean_tiled(
    const float* __restrict__ first,
    const float* __restrict__ second,
    const float* __restrict__ flow,
    const float* __restrict__ alpha,
    float* __restrict__ out)
{
    __shared__ float tile[C * TROWS * TSTR];  // 39,360 B

    // XCD-aware bijective swizzle (NWG % 8 == 0): each XCD owns a contiguous
    // range so neighboring tiles' halo re-reads hit its private L2.
    const int hw  = blockIdx.x;
    const int wid = (hw & (NXCD - 1)) * PERX + (hw >> 3);

    const int b   = wid / (NXT * NYT);
    const int r0  = wid - b * (NXT * NYT);
    const int tyi = r0 / NXT;
    const int txi = r0 - tyi * NXT;

    const int x_base = txi * TX;
    const int y_base = tyi * TY;
    const int x_lo   = x_base - R;     // multiple of 4 -> 16B-aligned float4 base
    const int y_lo   = y_base - R;

    const float* __restrict__ sec = second + (size_t)b * C * HW;
    const float* __restrict__ fst = first  + (size_t)b * C * HW;
    const float* __restrict__ fl  = flow   + (size_t)b * 2 * HW;
    float*       __restrict__ op  = out    + (size_t)b * HW;

    // wave n handles rows (n, n+8, n+16, n+24); lanes = consecutive x
    const int px  = threadIdx.x & 63;
    const int py0 = threadIdx.x >> 6;  // 0..7
    const int x   = x_base + px;

    // ---- Prefetch flow + first into registers BEFORE staging/barrier.
    //      Non-temporal: zero-reuse streams must not evict second's halo
    //      lines from L2. ----
    float pfx[4], pfy[4], pf0[4], pf1[4], pf2[4];
#pragma unroll
    for (int k = 0; k < 4; ++k) {
        const int p = (y_base + py0 + 8 * k) * W + x;
        pfx[k] = __builtin_nontemporal_load(fl + p);
        pfy[k] = __builtin_nontemporal_load(fl + HW + p);
        pf0[k] = __builtin_nontemporal_load(fst + p);
        pf1[k] = __builtin_nontemporal_load(fst + HW + p);
        pf2[k] = __builtin_nontemporal_load(fst + 2 * HW + p);
    }

    // ---- Stage clamped second-tile into LDS. Row-chunk-major with all 3
    //      channels unrolled per chunk: index/bounds/address math amortized
    //      over 3 planes (779 chunks -> 1.52 iters/thread vs 4.56 before).
    for (int j = threadIdx.x; j < TROWS * CPR; j += NT) {
        const int r   = j / CPR;
        const int q   = j - r * CPR;
        const int gy  = y_lo + r;
        const int gx0 = x_lo + 4 * q;
        float* __restrict__ dst = &tile[r * TSTR + 4 * q];
        if ((unsigned)gy < (unsigned)H && gx0 >= 0 && gx0 + 3 < W) {
            const int idx = gy * W + gx0;
            const float4 v0 = *reinterpret_cast<const float4*>(sec + idx);
            const float4 v1 = *reinterpret_cast<const float4*>(sec + HW + idx);
            const float4 v2 = *reinterpret_cast<const float4*>(sec + 2 * HW + idx);
            *reinterpret_cast<float4*>(dst)                     = v0;
            *reinterpret_cast<float4*>(dst + TROWS * TSTR)      = v1;
            *reinterpret_cast<float4*>(dst + 2 * TROWS * TSTR)  = v2;
        } else {
            // image-border tiles only: per-element clamped gather
            const int cyW = min(max(gy, 0), H - 1) * W;
            const int c0 = cyW + min(max(gx0,     0), W - 1);
            const int c1 = cyW + min(max(gx0 + 1, 0), W - 1);
            const int c2 = cyW + min(max(gx0 + 2, 0), W - 1);
            const int c3 = cyW + min(max(gx0 + 3, 0), W - 1);
#pragma unroll
            for (int ch = 0; ch < C; ++ch) {
                const float* __restrict__ src = sec + (size_t)ch * HW;
                float* d = dst + ch * (TROWS * TSTR);
                d[0] = src[c0]; d[1] = src[c1]; d[2] = src[c2]; d[3] = src[c3];
            }
        }
    }
    __syncthreads();

    const float a3 = alpha[0] * (1.0f / 3.0f);

#pragma unroll
    for (int k = 0; k < 4; ++k) {
        const int y = y_base + py0 + 8 * k;
        const int p = y * W + x;

        const float ix = (float)x + pfx[k] * ((float)W / (float)(W - 1));
        const float iy = (float)y + pfy[k] * ((float)H / (float)(H - 1));

        const float x0f = floorf(ix);
        const float y0f = floorf(iy);
        const float wx1 = ix - x0f;
        const float wy1 = iy - y0f;
        const float wx0 = 1.0f - wx1;
        const float wy0 = 1.0f - wy1;

        const int x0 = (int)x0f;
        const int y0 = (int)y0f;
        const int x1 = x0 + 1;
        const int y1 = y0 + 1;

        // validity from UNclipped coords; invalid corners contribute exactly 0
        // (mask the 1-D weights once; products inherit the masking)
        const float wxm0 = ((x0 >= 0) && (x0 < W)) ? wx0 : 0.0f;
        const float wxm1 = ((x1 >= 0) && (x1 < W)) ? wx1 : 0.0f;
        const float wym0 = ((y0 >= 0) && (y0 < H)) ? wy0 : 0.0f;
        const float wym1 = ((y1 >= 0) && (y1 < H)) ? wy1 : 0.0f;

        const float w00 = wym0 * wxm0;
        const float w01 = wym0 * wxm1;
        const float w10 = wym1 * wxm0;
        const float w11 = wym1 * wxm1;

        const int lx = x0 - x_lo;
        const int ly = y0 - y_lo;

        float acc;
        if ((unsigned)lx < (unsigned)(TCOLS - 1) &&
            (unsigned)ly < (unsigned)(TROWS - 1)) {
            // fast path: all 4 corners inside the staged tile (halo values are
            // clamped copies, but any out-of-image corner has weight == 0)
            const float* tp0 = &tile[ly * TSTR + lx];
            const float* tp1 = tp0 + TROWS * TSTR;
            const float* tp2 = tp0 + 2 * TROWS * TSTR;
            const float wa = w00 * tp0[0] + w01 * tp0[1] + w10 * tp0[TSTR] + w11 * tp0[TSTR + 1];
            const float wb = w00 * tp1[0] + w01 * tp1[1] + w10 * tp1[TSTR] + w11 * tp1[TSTR + 1];
            const float wc = w00 * tp2[0] + w01 * tp2[1] + w10 * tp2[TSTR] + w11 * tp2[TSTR + 1];
            acc = fabsf(pf0[k] - wa) + fabsf(pf1[k] - wb) + fabsf(pf2[k] - wc);
        } else {
            // rare fallback (|flow| > halo): identical math via global gather
            const int cx0 = min(max(x0, 0), W - 1);
            const int cx1 = min(max(x1, 0), W - 1);
            const int cy0 = min(max(y0, 0), H - 1);
            const int cy1 = min(max(y1, 0), H - 1);
            const int i00 = cy0 * W + cx0;
            const int i01 = cy0 * W + cx1;
            const int i10 = cy1 * W + cx0;
            const int i11 = cy1 * W + cx1;
            const float wa = w00 * sec[i00] + w01 * sec[i01] + w10 * sec[i10] + w11 * sec[i11];
            const float wb = w00 * sec[HW + i00] + w01 * sec[HW + i01] + w10 * sec[HW + i10] + w11 * sec[HW + i11];
            const float wc = w00 * sec[2*HW + i00] + w01 * sec[2*HW + i01] + w10 * sec[2*HW + i10] + w11 * sec[2*HW + i11];
            acc = fabsf(pf0[k] - wa) + fabsf(pf1[k] - wb) + fabsf(pf2[k] - wc);
        }

        __builtin_nontemporal_store(a3 * acc, op + p);
    }
}

extern "C" void kernel_launch(void* const* d_in, const int* in_sizes, int n_in,
                              void* d_out, int out_size, void* d_ws, size_t ws_size,
                              hipStream_t stream) {
    const float* first  = (const float*)d_in[0];
    const float* second = (const float*)d_in[1];
    const float* flow   = (const float*)d_in[2];
    const float* alpha  = (const float*)d_in[3];
    float* out = (float*)d_out;

    warp_l1_mean_tiled<<<NWG, NT, 0, stream>>>(first, second, flow, alpha, out);
}